// Round 1
// baseline (488.952 us; speedup 1.0000x reference)
//
#include <hip/hip_runtime.h>
#include <math.h>

#define NPTS 262144
#define KCL  256
#define DDIM 64
#define RROWS 16
#define NBLK (NPTS / RROWS)
#define ALPHA_DP 1.0f

// ws layout (float offsets):
//   [0 .. 16384)          WA_t[d][k]  = -0.5 * Elam[k,d]
//   [16384 .. 32768)      WB_t[d][k]  = Elam[k,d] * tau[k,d]
//   [32768 .. 33024)      base[k]
//   [33024]               kl_total
//   [33025 .. 33025+NBLK) per-block lse partials
#define OFF_WB   (DDIM * KCL)
#define OFF_BASE (2 * DDIM * KCL)
#define OFF_KL   (2 * DDIM * KCL + KCL)
#define OFF_PART (2 * DDIM * KCL + KCL + 1)

__device__ __forceinline__ float digamma_f(float x) {
  // push x >= 6 via psi(x) = psi(x+1) - 1/x, then asymptotic series
  float r = 0.0f;
  while (x < 6.0f) { r -= 1.0f / x; x += 1.0f; }
  float inv  = 1.0f / x;
  float inv2 = inv * inv;
  return r + logf(x) - 0.5f * inv
       - inv2 * (0.083333333333333333f
         - inv2 * (0.008333333333333333f
           - inv2 * 0.003968253968253968f));
}

__global__ void dpmm_prep(const float* __restrict__ u, const float* __restrict__ v,
                          const float* __restrict__ tau, const float* __restrict__ c,
                          const float* __restrict__ n, const float* __restrict__ B,
                          const float* __restrict__ tau0, const float* __restrict__ c0,
                          const float* __restrict__ n0, const float* __restrict__ B0,
                          float* __restrict__ ws) {
  __shared__ float eb_s[KCL], e1b_s[KCL], elogpi_s[KCL];
  __shared__ double kl_s[KCL];
  const int k = threadIdx.x;

  float uk = u[k], vk = v[k];
  float dig_sum = digamma_f(uk + vk);
  float eb  = digamma_f(uk) - dig_sum;
  float e1b = digamma_f(vk) - dig_sum;
  eb_s[k] = eb; e1b_s[k] = e1b;
  __syncthreads();
  if (k == 0) {
    float run = 0.0f;
    for (int j = 0; j < KCL; ++j) { elogpi_s[j] = eb_s[j] + run; run += e1b_s[j]; }
  }
  __syncthreads();

  float nk = n[k], ck = c[k], n0k = n0[k], c0k = c0[k];
  float a = 0.5f * nk, a0 = 0.5f * n0k;
  float dga  = digamma_f(a);
  float lga  = lgammaf(a);
  float lga0 = lgammaf(a0);

  float  sumNegLogB = 0.0f, sumElamTau2 = 0.0f;
  double klg = 0.0, knq = 0.0;
  for (int d = 0; d < DDIM; ++d) {
    float Bkd  = B[k * DDIM + d];
    float tkd  = tau[k * DDIM + d];
    float B0kd = B0[k * DDIM + d];
    float t0kd = tau0[k * DDIM + d];
    float Elam = nk / Bkd;
    ws[d * KCL + k]          = -0.5f * Elam;   // WA_t
    ws[OFF_WB + d * KCL + k] = Elam * tkd;     // WB_t
    sumNegLogB  -= logf(Bkd);
    sumElamTau2 += Elam * tkd * tkd;
    float b = 0.5f * Bkd, b0 = 0.5f * B0kd;
    klg += (double)((a - a0) * dga - lga + lga0
                    + a0 * (logf(b) - logf(b0)) + a * (b0 - b) / b);
    float dt = tkd - t0kd;
    knq += (double)(Elam * dt * dt);
  }
  float sumEloglam = (float)DDIM * (dga + 0.6931471805599453f) + sumNegLogB;
  ws[OFF_BASE + k] = elogpi_s[k]
      + 0.5f * (sumEloglam - (float)DDIM * 1.8378770664093453f
                - (float)DDIM / ck - sumElamTau2);

  float klb = lgammaf(uk + vk) - lgammaf(uk) - lgammaf(vk)
            - (lgammaf(1.0f + ALPHA_DP) - lgammaf(ALPHA_DP))
            + (uk - 1.0f) * eb + (vk - ALPHA_DP) * e1b;
  float kln = 0.5f * (float)DDIM * (c0k / ck - 1.0f + logf(ck / c0k))
            + 0.5f * c0k * (float)knq;
  kl_s[k] = (double)klb + klg + (double)kln;
  __syncthreads();
  if (k == 0) {
    double tot = 0.0;
    for (int j = 0; j < KCL; ++j) tot += kl_s[j];
    ws[OFF_KL] = (float)tot;
  }
}

__global__ __launch_bounds__(64) void dpmm_main(
    const float* __restrict__ x,
    const float* __restrict__ WA, const float* __restrict__ WB,
    const float* __restrict__ base,
    float* __restrict__ pi, float* __restrict__ partial) {
  const int t = threadIdx.x;            // 0..63 (one wave)
  const long row0 = (long)blockIdx.x * RROWS;

  __shared__ float2 xx[RROWS][DDIM];    // (x, x^2); broadcast reads -> no conflicts
  for (int f = t; f < RROWS * DDIM; f += 64) {
    int i = f >> 6, d = f & 63;
    float xv = x[(row0 + i) * DDIM + d];
    xx[i][d] = make_float2(xv, xv * xv);
  }
  __syncthreads();

  float acc[4][RROWS];
  #pragma unroll
  for (int j = 0; j < 4; ++j) {
    float bb = base[t + 64 * j];
    #pragma unroll
    for (int i = 0; i < RROWS; ++i) acc[j][i] = bb;
  }

  #pragma unroll 4
  for (int d = 0; d < DDIM; ++d) {
    float wa[4], wb[4];
    #pragma unroll
    for (int j = 0; j < 4; ++j) {
      wa[j] = WA[d * KCL + t + 64 * j];
      wb[j] = WB[d * KCL + t + 64 * j];
    }
    #pragma unroll
    for (int i = 0; i < RROWS; ++i) {
      float2 vv = xx[i][d];
      #pragma unroll
      for (int j = 0; j < 4; ++j)
        acc[j][i] = fmaf(wa[j], vv.y, fmaf(wb[j], vv.x, acc[j][i]));
    }
  }

  float lsum = 0.0f;
  #pragma unroll 1
  for (int i = 0; i < RROWS; ++i) {
    float m = fmaxf(fmaxf(acc[0][i], acc[1][i]), fmaxf(acc[2][i], acc[3][i]));
    #pragma unroll
    for (int off = 32; off; off >>= 1) m = fmaxf(m, __shfl_xor(m, off, 64));
    float e[4];
    float s = 0.0f;
    #pragma unroll
    for (int j = 0; j < 4; ++j) { e[j] = __expf(acc[j][i] - m); s += e[j]; }
    #pragma unroll
    for (int off = 32; off; off >>= 1) s += __shfl_xor(s, off, 64);
    float rs = 1.0f / s;
    size_t o = (size_t)(row0 + i) * KCL + t;
    #pragma unroll
    for (int j = 0; j < 4; ++j) pi[o + 64 * j] = e[j] * rs;   // coalesced
    lsum += m + __logf(s);                                    // wave-uniform
  }
  if (t == 0) partial[blockIdx.x] = lsum;
}

__global__ void dpmm_fin(const float* __restrict__ partial,
                         const float* __restrict__ kl,
                         float* __restrict__ out_elbo) {
  __shared__ double red[256];
  const int t = threadIdx.x;
  double s = 0.0;
  for (int i = t; i < NBLK; i += 256) s += (double)partial[i];
  red[t] = s;
  __syncthreads();
  for (int off = 128; off; off >>= 1) {
    if (t < off) red[t] += red[t + off];
    __syncthreads();
  }
  if (t == 0) out_elbo[0] = (float)(red[0] - (double)kl[0]);
}

extern "C" void kernel_launch(void* const* d_in, const int* in_sizes, int n_in,
                              void* d_out, int out_size, void* d_ws, size_t ws_size,
                              hipStream_t stream) {
  const float* x    = (const float*)d_in[0];
  const float* u    = (const float*)d_in[1];
  const float* v    = (const float*)d_in[2];
  const float* tau  = (const float*)d_in[3];
  const float* c    = (const float*)d_in[4];
  const float* n    = (const float*)d_in[5];
  const float* B    = (const float*)d_in[6];
  const float* tau0 = (const float*)d_in[7];
  const float* c0   = (const float*)d_in[8];
  const float* n0   = (const float*)d_in[9];
  const float* B0   = (const float*)d_in[10];

  float* out = (float*)d_out;
  float* ws  = (float*)d_ws;

  dpmm_prep<<<1, KCL, 0, stream>>>(u, v, tau, c, n, B, tau0, c0, n0, B0, ws);

  const float* WA   = ws;
  const float* WB   = ws + OFF_WB;
  const float* base = ws + OFF_BASE;
  const float* kl   = ws + OFF_KL;
  float* partial    = ws + OFF_PART;

  dpmm_main<<<NBLK, 64, 0, stream>>>(x, WA, WB, base, out, partial);
  dpmm_fin<<<1, 256, 0, stream>>>(partial, kl, out + (size_t)NPTS * KCL);
}